// Round 3
// 269.357 us; speedup vs baseline: 1.0643x; 1.0643x over previous
//
#include <hip/hip_runtime.h>

typedef __attribute__((ext_vector_type(8))) short bf16x8;
typedef __attribute__((ext_vector_type(4))) float f32x4;

#define BB 1024
#define TT 256
#define DD 63
#define HH 128
#define CHUNK 4    // 4 batch rows/block, grid 256 = 1 block/CU
#define HSTR 160   // shorts; 80 dwords ≡ 16 (mod 32): broadcast b128 reads exactly 2-way (free)
#define XSTR 96    // shorts; 48 dwords ≡ 16 (mod 32)

// Barrier that drains only LDS (lgkmcnt), NOT outstanding global loads.
#define LDS_BARRIER() asm volatile("s_waitcnt lgkmcnt(0)\n\ts_barrier" ::: "memory")

__device__ __forceinline__ short f2bf(float f) {
  unsigned u = __builtin_bit_cast(unsigned, f);
  u = (u + 0x7FFFu + ((u >> 16) & 1u)) >> 16;   // RNE
  return (short)u;
}
__device__ __forceinline__ float sigm(float x) {
  return __builtin_amdgcn_rcpf(1.f + __expf(-x));
}
__device__ __forceinline__ float tanh_fast(float x) {
  float e = __expf(2.f * x);
  return 1.f - 2.f * __builtin_amdgcn_rcpf(e + 1.f);
}

// R11 = R10 fwd t-loop (UNCHANGED: transposed GEMM + duplicate-group, 1
// elem/lane, per-gate staggered MFMA chains, one lgkm-only barrier/step)
// + FUSED epilogue replacing the second kernel entirely:
//   - backward dir = ONE cell step on x[:,T-1] (h0=c0=0), fp32 scalar math
//     identical to the R10 bwd kernel (no new bf16 error; absmax has no
//     headroom),
//   - full FC (fwd half + bwd half + bias) in-block.
// Rationale: total-minus-fwd was ~75us while a bottom-up model of the bwd
// kernel says ~10us; fusing removes the inter-kernel serialization (bwd did
// `out +=` behind fwd), the extra launch, and the bwd kernel itself, at a
// predicted cost of +3-5us of epilogue inside the fwd kernel.
// Kept: launch_bounds min-waves=2 (R4: VGPR clamp => weight spill); grid=256
// = 1 block/CU (R5); HSTR=160/XSTR=96 (R7: 136 => 4-8-way conflicts).
// (Resubmitted unchanged: R11 and R12 both hit GPUAcquisitionTimeout — the
// fusion hypothesis has never been measured.)
__global__ __launch_bounds__(512, 2)
void bilstm_fused_kernel(const float* __restrict__ X,
                         const float* __restrict__ Wih,
                         const float* __restrict__ Whh,
                         const float* __restrict__ bih,
                         const float* __restrict__ bhh,
                         const float* __restrict__ Wih_b,
                         const float* __restrict__ bih_b,
                         const float* __restrict__ bhh_b,
                         const float* __restrict__ Wfc,
                         const float* __restrict__ bfc,
                         float* __restrict__ out) {
  __shared__ __align__(16) short hbuf[2 * 4 * HSTR];   // h^T (bf16), rows=batch 0..3, dbuf
  __shared__ __align__(16) short xbuf[2 * 4 * XSTR];   // x^T (bf16), rows=batch 0..3, 2 slots
  __shared__ __align__(16) float fst[4 * 256];         // epilogue [h_f ; h_b] per batch
  __shared__ __align__(16) float xl[4 * 64];           // x_last fp32, pad 64
  __shared__ __align__(16) float glb[4 * 512];         // bwd gate pre-acts [b][n]

  const int tid  = threadIdx.x;
  const int wave = tid >> 6;
  const int lane = tid & 63;
  const int quad = lane >> 4;
  const int l15  = lane & 15;
  const int b0   = blockIdx.x * CHUNK;
  const int br   = l15 & 3;        // this lane's batch row
  // duplicate-group index p = l15>>2 selects which acc register is valid

  // ---- register-resident W fragments as MFMA A operands ----
  bf16x8 Ah[4][4];   // [gate][kstep], W_hh
  bf16x8 Axw[4][2];  // [gate][kstep], W_ih (K padded 63->64)
  f32x4  bias[4];    // bias per acc reg q: col = wave*16 + quad*4 + q
#pragma unroll
  for (int g = 0; g < 4; ++g) {
    const int n = g * 128 + wave * 16 + l15;
    const float* wr = Whh + (size_t)n * HH;
#pragma unroll
    for (int ks = 0; ks < 4; ++ks) {
      const int k0 = ks * 32 + quad * 8;
      f32x4 w0 = *(const f32x4*)(wr + k0);
      f32x4 w1 = *(const f32x4*)(wr + k0 + 4);
      bf16x8 v;
#pragma unroll
      for (int jj = 0; jj < 4; ++jj) { v[jj] = f2bf(w0[jj]); v[4 + jj] = f2bf(w1[jj]); }
      Ah[g][ks] = v;
    }
    const float* xr = Wih + (size_t)n * DD;
#pragma unroll
    for (int ks = 0; ks < 2; ++ks) {
      const int k0 = ks * 32 + quad * 8;
      bf16x8 v;
#pragma unroll
      for (int jj = 0; jj < 8; ++jj) {
        const int k = k0 + jj;
        v[jj] = (k < DD) ? f2bf(xr[k]) : (short)0;
      }
      Axw[g][ks] = v;
    }
    const int cb = g * 128 + wave * 16 + quad * 4;
    f32x4 b1 = *(const f32x4*)&bih[cb];
    f32x4 b2 = *(const f32x4*)&bhh[cb];
    bias[g] = b1 + b2;
  }

  // zero h buffers (h(0)=0); x pad columns zeroed once (both slots)
  for (int i = tid; i < 2 * 4 * HSTR; i += 512) hbuf[i] = 0;
  if (tid >= CHUNK * DD && tid < 256) {
    const int rr = tid & 3;
    xbuf[rr * XSTR + DD] = 0;
    xbuf[4 * XSTR + rr * XSTR + DD] = 0;
  }

  // x staging (R8 mapping): 4 rows x 63 cols = 252 threads, distance-2
  const int xrow = tid / DD;
  const int xd   = tid - xrow * DD;
  const bool xthr = (tid < CHUNK * DD);
  const float* xptr = X + ((size_t)(b0 + xrow) * TT) * DD + xd;
  float xv_pend = 0.f;
  if (xthr) {
    xbuf[xrow * XSTR + xd] = f2bf(xptr[0]);   // slot 0 = x(0)
    xv_pend = xptr[DD];                        // x(1)
    xptr += 2 * DD;
  }
  __syncthreads();

  float cc = 0.f, hv = 0.f;   // ONE element per lane: (batch=br, col=wave*16+quad*4+p)
  const int hcol = wave * 16 + quad * 4 + (l15 >> 2);
  const bool s0 = (l15 & 4) != 0;
  const bool s1 = (l15 & 8) != 0;

  for (int t = 0; t < TT; ++t) {
    const int xcur = (t & 1) * (4 * XSTR);
    const int hcur = (t & 1) * (4 * HSTR);

    // issue x(t+2) early; stays in flight across the lgkm-only barrier
    float xv_new = 0.f;
    const bool pf2 = xthr && (t + 2 < TT);
    if (pf2) { xv_new = *xptr; xptr += DD; }

    // B-fragments: row br (l15&3) -> 4-way same-address broadcast, 2-way banks
    bf16x8 Bh_[4], Bx_[2];
#pragma unroll
    for (int ks = 0; ks < 4; ++ks)
      Bh_[ks] = *(const bf16x8*)&hbuf[hcur + br * HSTR + ks * 32 + quad * 8];
#pragma unroll
    for (int ks = 0; ks < 2; ++ks)
      Bx_[ks] = *(const bf16x8*)&xbuf[xcur + br * XSTR + ks * 32 + quad * 8];

    // ---- per-gate staggered: 6-MFMA dependent chain, then THAT gate's
    //      select+activation (overlaps the next gate's MFMA issue) ----
    float gact[4];
#pragma unroll
    for (int g = 0; g < 4; ++g) {
      f32x4 a = __builtin_amdgcn_mfma_f32_16x16x32_bf16(Ah[g][0], Bh_[0], bias[g], 0, 0, 0);
      a = __builtin_amdgcn_mfma_f32_16x16x32_bf16(Ah[g][1], Bh_[1], a, 0, 0, 0);
      a = __builtin_amdgcn_mfma_f32_16x16x32_bf16(Ah[g][2], Bh_[2], a, 0, 0, 0);
      a = __builtin_amdgcn_mfma_f32_16x16x32_bf16(Ah[g][3], Bh_[3], a, 0, 0, 0);
      a = __builtin_amdgcn_mfma_f32_16x16x32_bf16(Axw[g][0], Bx_[0], a, 0, 0, 0);
      a = __builtin_amdgcn_mfma_f32_16x16x32_bf16(Axw[g][1], Bx_[1], a, 0, 0, 0);
      const float a01 = s0 ? a[1] : a[0];
      const float a23 = s0 ? a[3] : a[2];
      const float v = s1 ? a23 : a01;
      gact[g] = (g == 2) ? tanh_fast(v) : sigm(v);
    }

    // ---- short exposed tail ----
    cc = gact[1] * cc + gact[0] * gact[2];
    hv = gact[3] * tanh_fast(cc);
    hbuf[(hcur ^ (4 * HSTR)) + br * HSTR + hcol] = f2bf(hv);

    if (xthr && (t + 1 < TT))
      xbuf[(xcur ^ (4 * XSTR)) + xrow * XSTR + xd] = f2bf(xv_pend);
    xv_pend = xv_new;
    LDS_BARRIER();   // the ONE barrier: h/x produced -> consumed next step
  }

  // ==================== fused epilogue ====================
  // stage h_f (fwd half) and x_last for the backward one-step cell
  fst[br * 256 + hcol] = hv;
  if (xthr)
    xl[xrow * 64 + xd] = X[((size_t)(b0 + xrow) * TT + (TT - 1)) * DD + xd];
  __syncthreads();

  // backward gate pre-activations, fp32 (identical math to old bwd kernel):
  // thread n covers gate-row n for all 4 batches; x_last broadcast from LDS
  {
    const int n = tid;                       // 0..511
    const float* wr = Wih_b + (size_t)n * DD;
    const float bb2 = bih_b[n] + bhh_b[n];
    float a0 = bb2, a1 = bb2, a2 = bb2, a3 = bb2;
    for (int k = 0; k < DD; ++k) {
      const float w = wr[k];
      a0 += w * xl[0 * 64 + k];
      a1 += w * xl[1 * 64 + k];
      a2 += w * xl[2 * 64 + k];
      a3 += w * xl[3 * 64 + k];
    }
    glb[0 * 512 + n] = a0;
    glb[1 * 512 + n] = a1;
    glb[2 * 512 + n] = a2;
    glb[3 * 512 + n] = a3;
  }
  __syncthreads();

  // backward cell (f*c0 = 0): h_b = o * tanh(i*g)
  {
    const int b = tid >> 7, j = tid & 127;   // 4 b x 128 j = 512 threads
    const float iv = sigm(glb[b * 512 + j]);
    const float gv = tanh_fast(glb[b * 512 + 256 + j]);
    const float ov = sigm(glb[b * 512 + 384 + j]);
    fst[b * 256 + 128 + j] = ov * tanh_fast(iv * gv);
  }
  __syncthreads();

  // full FC (+ bias) on [h_f ; h_b]
  if (tid < CHUNK * 14) {
    const int rr = tid / 14, o = tid - rr * 14;
    const float* wr = Wfc + (size_t)o * (2 * HH);
    float acc = bfc[o];
#pragma unroll 16
    for (int k = 0; k < 2 * HH; ++k) acc += wr[k] * fst[rr * 256 + k];
    out[(size_t)(b0 + rr) * 14 + o] = acc;
  }
}

extern "C" void kernel_launch(void* const* d_in, const int* in_sizes, int n_in,
                              void* d_out, int out_size, void* d_ws, size_t ws_size,
                              hipStream_t stream) {
  const float* X     = (const float*)d_in[0];
  const float* Wih_f = (const float*)d_in[1];
  const float* Whh_f = (const float*)d_in[2];
  const float* bih_f = (const float*)d_in[3];
  const float* bhh_f = (const float*)d_in[4];
  const float* Wih_b = (const float*)d_in[5];
  // d_in[6] = W_hh_b: unused (backward dir needs only one step from zero state)
  const float* bih_b = (const float*)d_in[7];
  const float* bhh_b = (const float*)d_in[8];
  const float* Wfc   = (const float*)d_in[9];
  const float* bfc   = (const float*)d_in[10];
  float* out = (float*)d_out;

  bilstm_fused_kernel<<<BB / CHUNK, 512, 0, stream>>>(
      X, Wih_f, Whh_f, bih_f, bhh_f, Wih_b, bih_b, bhh_b, Wfc, bfc, out);
}